// Round 8
// baseline (531.110 us; speedup 1.0000x reference)
//
#include <hip/hip_runtime.h>
#include <math.h>

#define T_LEN 1024
#define BATCH 512
#define DIN   12
#define HID   100
#define G4    400
#define MB    4                   // batches per block, at C-rows {0,4,8,12}
#define NBLK  (BATCH / MB)        // 128
#define AROW  160                 // halves per A row -> 320 B stride
#define NW    8
#define NTHR  (NW * 64)           // 512
#define CHUNK 64
#define UNROLL 8

typedef _Float16 half8   __attribute__((ext_vector_type(8)));
typedef _Float16 half4_t __attribute__((ext_vector_type(4)));
typedef float    f32x4   __attribute__((ext_vector_type(4)));

static __device__ __forceinline__ float fast_exp2(float v) {
#if __has_builtin(__builtin_amdgcn_exp2f)
    return __builtin_amdgcn_exp2f(v);
#else
    return exp2f(v);
#endif
}
static __device__ __forceinline__ float fast_rcp(float v) {
#if __has_builtin(__builtin_amdgcn_rcpf)
    return __builtin_amdgcn_rcpf(v);
#else
    return 1.0f / v;
#endif
}

// LDS-only barrier, single asm: the "memory" clobber pins all memory ops
// (h ds_writes stay above, a ds_reads stay below) but leaves VALU/MFMA
// address-calc free to be scheduled across the wait.
// No vmcnt drain: out-store bursts stay fire-and-forget.
static __device__ __forceinline__ void wg_barrier_lds() {
    asm volatile("s_waitcnt lgkmcnt(0)\n\ts_barrier" ::: "memory");
}

// R7 structure (best measured: 485-497us). Round-8 single change:
// DEPTH-2 CHAIN SPLIT — each gate = two depth-2 C-operand chains
// (kt{0,1} from biasC, kt{2,3} from zero) combined by ONE scalar add on
// reg 0 (the only consumed element). Shaves ~2 dependent-MFMA latencies
// off the acc->exp2 critical path. Distinct from R1's falsified depth-1
// (64 acc regs + 12 VALU adds); here 32 acc regs + 4 scalar adds.
// Retained wins: lgkm-only barrier, pre-scaled weights, bias-as-C,
// T14-split refill (loads 1 step early), gate order {0,2,1,3}, burst
// stores, wave-7 stage-before-MFMA hoist.
__launch_bounds__(NTHR, 2)
__global__ void lstm_mfma_kernel(const float* __restrict__ x,
                                 const float* __restrict__ Wx,
                                 const float* __restrict__ Wh,
                                 const float* __restrict__ b,
                                 const float* __restrict__ Wd,
                                 const float* __restrict__ bd,
                                 float* __restrict__ out) {
    __shared__ __align__(16) char smem[65536];
    const int tid  = threadIdx.x;
    const int wid  = tid >> 6;
    const int lane = tid & 63;
    const int l    = lane & 15;
    const int quad = lane >> 4;
    const int b0   = blockIdx.x * MB;
    const int j    = wid * 16 + l;

    const float L2E = 1.4426950408889634f;

    // ---------- prologue: B fragments staged through LDS ----------
    _Float16* stage = (_Float16*)smem;      // [8][8][512] halves = 64 KB
    half8 bfrag[4][4];                       // wave 7 uses only bfrag[0] (= Wd cols)
#pragma unroll
    for (int pass = 0; pass < 2; ++pass) {
#pragma unroll
        for (int gg = 0; gg < 2; ++gg) {
            const int G = pass * 2 + gg;
            const float gsc = (G == 2) ? (-2.f * L2E) : (-L2E);  // gate pre-scale
#pragma unroll
            for (int kt = 0; kt < 4; ++kt) {
                half8 v;
#pragma unroll
                for (int jj = 0; jj < 8; ++jj) {
                    const int k = kt * 32 + quad * 8 + jj;
                    float w = 0.f;
                    if (wid < 7) {
                        if (j < HID) {
                            if (k < HID)            w = Wh[k * G4 + G * HID + j] * gsc;
                            else if (k < HID + DIN) w = Wx[(k - HID) * G4 + G * HID + j] * gsc;
                        }
                    } else if (G == 0) {
                        if (l < DIN && k < HID)     w = Wd[k * DIN + l];   // unscaled
                    }
                    v[jj] = (_Float16)w;
                }
                *(half8*)&stage[((wid * 8) + (gg * 4 + kt)) * 512 + lane * 8] = v;
            }
        }
        __syncthreads();
#pragma unroll
        for (int gg = 0; gg < 2; ++gg)
#pragma unroll
            for (int kt = 0; kt < 4; ++kt)
                bfrag[pass * 2 + gg][kt] =
                    *(half8*)&stage[((wid * 8) + (gg * 4 + kt)) * 512 + lane * 8];
        __syncthreads();
    }

    // persistent bias-C registers (C operand of the first MFMA in each chain)
    f32x4 biasC[4];
#pragma unroll
    for (int G = 0; G < 4; ++G) biasC[G] = (f32x4){0.f, 0.f, 0.f, 0.f};
    if (wid < 7) {
        if (j < HID) {
#pragma unroll
            for (int G = 0; G < 4; ++G) {
                const float gsc = (G == 2) ? (-2.f * L2E) : (-L2E);
                const float bv = b[G * HID + j] * gsc;
                biasC[G] = (f32x4){bv, bv, bv, bv};
            }
        }
    } else if (l < DIN) {
        const float bv = bd[l];
        biasC[0] = (f32x4){bv, bv, bv, bv};
    }

    // ---------- LDS after prologue: 4-row A dbuf (320B stride) + x chunk ----------
    _Float16 (*Ah)[MB][AROW] = (_Float16 (*)[MB][AROW])smem;     // 2*4*160*2 = 2560 B
    _Float16* xchunk = (_Float16*)(smem + 2560);                 // 64*48*2 = 6144 B

    // T14-split refill: loads one step early into regs, stores next step.
    float4 pre0 = {0.f, 0.f, 0.f, 0.f}, pre1 = {0.f, 0.f, 0.f, 0.f};
    auto refill_load = [&](int c) {   // issue HBM loads for x[c*64 .. +63]
        {
            const int f  = tid;                              // < 768
            const int m  = f / (CHUNK * DIN / 4);            // /192
            const int o  = f - m * (CHUNK * DIN / 4);
            const int tt = o / 3;
            const int dd = o - tt * 3;
            pre0 = *(const float4*)(x +
                ((size_t)(b0 + m) * T_LEN + c * CHUNK + tt) * DIN + dd * 4);
        }
        if (tid < (CHUNK * MB * DIN) / 4 - NTHR) {           // tid < 256
            const int f  = tid + NTHR;
            const int m  = f / (CHUNK * DIN / 4);
            const int o  = f - m * (CHUNK * DIN / 4);
            const int tt = o / 3;
            const int dd = o - tt * 3;
            pre1 = *(const float4*)(x +
                ((size_t)(b0 + m) * T_LEN + c * CHUNK + tt) * DIN + dd * 4);
        }
    };
    auto refill_store = [&]() {       // convert + ds_write (waits vmcnt here)
        {
            const int f  = tid;
            const int m  = f / (CHUNK * DIN / 4);
            const int o  = f - m * (CHUNK * DIN / 4);
            const int tt = o / 3;
            const int dd = o - tt * 3;
            half4_t h4;
            h4[0] = (_Float16)pre0.x; h4[1] = (_Float16)pre0.y;
            h4[2] = (_Float16)pre0.z; h4[3] = (_Float16)pre0.w;
            *(half4_t*)&xchunk[tt * (MB * DIN) + m * DIN + dd * 4] = h4;
        }
        if (tid < (CHUNK * MB * DIN) / 4 - NTHR) {
            const int f  = tid + NTHR;
            const int m  = f / (CHUNK * DIN / 4);
            const int o  = f - m * (CHUNK * DIN / 4);
            const int tt = o / 3;
            const int dd = o - tt * 3;
            half4_t h4;
            h4[0] = (_Float16)pre1.x; h4[1] = (_Float16)pre1.y;
            h4[2] = (_Float16)pre1.z; h4[3] = (_Float16)pre1.w;
            *(half4_t*)&xchunk[tt * (MB * DIN) + m * DIN + dd * 4] = h4;
        }
    };

    for (int i = tid; i < (2 * MB * AROW) / 2; i += NTHR) ((int*)smem)[i] = 0;
    refill_load(0);
    refill_store();
    __syncthreads();
    if (tid < MB * 3) {           // stage x[0]
        const int m = tid / 3, part = tid - (tid / 3) * 3;
        *(half4_t*)&Ah[0][m][HID + part * 4] =
            *(const half4_t*)&xchunk[m * DIN + part * 4];
    }
    __syncthreads();

    const bool gate_lane = (wid < 7) && (j < HID);
    const int  arow = l >> 2;
    const f32x4 kZ = (f32x4){0.f, 0.f, 0.f, 0.f};

    float cs = 0.f;               // scaled cell state  c' = -2*log2e * c
    float obuf[UNROLL];

#pragma unroll 1
    for (int tb = 0; tb < T_LEN / UNROLL; ++tb) {
        const bool do_refill = (((tb + 1) & 7) == 0) && ((tb + 1) < T_LEN / UNROLL);
#pragma unroll
        for (int it = 0; it < UNROLL; ++it) {
            const int t  = tb * UNROLL + it;     // always < T_LEN here
            const int p  = it & 1;               // compile-time parity
            const int pn = p ^ 1;

            if (it == UNROLL - 2) {
                if (do_refill) refill_load((tb + 1) >> 3);   // loads in flight 1 step
            }
            if (it == UNROLL - 1) {
                if (do_refill) {
                    refill_store();               // vmcnt covered by prev step
                    wg_barrier_lds();
                }
            }

            half8 a[4];
#pragma unroll
            for (int kt = 0; kt < 4; ++kt)
                a[kt] = *(const half8*)&Ah[p][arow][kt * 32 + quad * 8];

            if (wid < 7) {
                // DEPTH-2 SPLIT: per gate, chain L (kt 0-1, seeded biasC)
                // and chain H (kt 2-3, seeded 0) run as 8 independent
                // depth-2 chains; combined by one scalar add on reg 0.
                // Gate order {0,2,1,3}: g-gate heads the longest activation
                // sub-chain, o-gate is consumed last. All indices
                // compile-time (R5 lesson).
                f32x4 accL[4], accH[4];
#pragma unroll
                for (int kt = 0; kt < 2; ++kt)
#pragma unroll
                    for (int Gi = 0; Gi < 4; ++Gi) {
                        constexpr int GO_[4] = {0, 2, 1, 3};
                        const int G = GO_[Gi];   // compile-time after unroll
                        accL[G] = __builtin_amdgcn_mfma_f32_16x16x32_f16(
                                      a[kt], bfrag[G][kt],
                                      (kt == 0) ? biasC[G] : accL[G], 0, 0, 0);
                    }
#pragma unroll
                for (int kt = 2; kt < 4; ++kt)
#pragma unroll
                    for (int Gi = 0; Gi < 4; ++Gi) {
                        constexpr int GO_[4] = {0, 2, 1, 3};
                        const int G = GO_[Gi];
                        accH[G] = __builtin_amdgcn_mfma_f32_16x16x32_f16(
                                      a[kt], bfrag[G][kt],
                                      (kt == 2) ? kZ : accH[G], 0, 0, 0);
                    }

                if (gate_lane) {
                    // pre-scaled: zi,zf,zo = -log2e * a ; zg = -2log2e * a
                    const float ei = fast_exp2(accL[0][0] + accH[0][0]);
                    const float ef = fast_exp2(accL[1][0] + accH[1][0]);
                    const float eg = fast_exp2(accL[2][0] + accH[2][0]);
                    const float eo = fast_exp2(accL[3][0] + accH[3][0]);
                    const float gf  = fast_rcp(1.f + ef);
                    const float dd  = (1.f + ei) * (1.f + eg);
                    const float u   = __builtin_fmaf(eg, 2.f * L2E, -2.f * L2E); // -2log2e*(1-eg)
                    const float gig = u * fast_rcp(dd);          // -2log2e * sig(i)*tanh(g)
                    cs = __builtin_fmaf(gf, cs, gig);            // c' = gf*c' + gig'
                    const float ec = fast_exp2(cs);              // e^{-2 c}
                    const float hv = (1.f - ec) * fast_rcp((1.f + eo) * (1.f + ec));
                    Ah[pn][quad][j] = (_Float16)hv;
                }
            } else {
                // wave 7: stage x[t+1] FIRST (independent of a[]), so the
                // LDS write latency hides under the projection MFMAs.
                if ((t + 1) < T_LEN && lane < MB * 3) {
                    const int m = lane / 3, part = lane - (lane / 3) * 3;
                    *(half4_t*)&Ah[pn][m][HID + part * 4] =
                        *(const half4_t*)&xchunk[((t + 1) & (CHUNK - 1)) * (MB * DIN)
                                                 + m * DIN + part * 4];
                }
                f32x4 accP;
#pragma unroll
                for (int kt = 0; kt < 4; ++kt)
                    accP = __builtin_amdgcn_mfma_f32_16x16x32_f16(
                               a[kt], bfrag[0][kt],
                               (kt == 0) ? biasC[0] : accP, 0, 0, 0);
                obuf[it] = accP[0];               // out row t-1, batch=quad, col=l
            }
            wg_barrier_lds();
        }
        if (wid == 7 && l < DIN) {
            // burst stores, never drained (lgkm-only barriers) -> fire-and-forget
#pragma unroll
            for (int s = 0; s < UNROLL; ++s) {
                const int row = tb * UNROLL + s - 1;
                if (row >= 0)
                    out[((size_t)(b0 + quad) * T_LEN + row) * DIN + l] = obuf[s];
            }
        }
    }

    // ---------- epilogue: projection of h_{T-1} -> out row T-1 ----------
    if (wid == 7) {
        half8 a[4];
#pragma unroll
        for (int kt = 0; kt < 4; ++kt)
            a[kt] = *(const half8*)&Ah[0][arow][kt * 32 + quad * 8];
        f32x4 accP;
#pragma unroll
        for (int kt = 0; kt < 4; ++kt)
            accP = __builtin_amdgcn_mfma_f32_16x16x32_f16(
                       a[kt], bfrag[0][kt],
                       (kt == 0) ? biasC[0] : accP, 0, 0, 0);
        if (l < DIN)
            out[((size_t)(b0 + quad) * T_LEN + (T_LEN - 1)) * DIN + l] = accP[0];
    }
}

extern "C" void kernel_launch(void* const* d_in, const int* in_sizes, int n_in,
                              void* d_out, int out_size, void* d_ws, size_t ws_size,
                              hipStream_t stream) {
    const float* x  = (const float*)d_in[0];
    const float* Wx = (const float*)d_in[1];
    const float* Wh = (const float*)d_in[2];
    const float* b  = (const float*)d_in[3];
    const float* Wd = (const float*)d_in[4];
    const float* bd = (const float*)d_in[5];
    float* out = (float*)d_out;

    lstm_mfma_kernel<<<NBLK, NTHR, 0, stream>>>(x, Wx, Wh, b, Wd, bd, out);
}

// Round 9
// 530.781 us; speedup vs baseline: 1.0006x; 1.0006x over previous
//
#include <hip/hip_runtime.h>
#include <math.h>

#define T_LEN 1024
#define BATCH 512
#define DIN   12
#define HID   100
#define G4    400
#define MB    4                   // batches per block, at C-rows {0,4,8,12}
#define NBLK  (BATCH / MB)        // 128
#define AROW  160                 // halves per A row -> 320 B stride
#define NW    8
#define NTHR  (NW * 64)           // 512
#define CHUNK 64
#define UNROLL 8

typedef _Float16 half8   __attribute__((ext_vector_type(8)));
typedef _Float16 half4_t __attribute__((ext_vector_type(4)));
typedef float    f32x4   __attribute__((ext_vector_type(4)));

static __device__ __forceinline__ float fast_exp2(float v) {
#if __has_builtin(__builtin_amdgcn_exp2f)
    return __builtin_amdgcn_exp2f(v);
#else
    return exp2f(v);
#endif
}
static __device__ __forceinline__ float fast_rcp(float v) {
#if __has_builtin(__builtin_amdgcn_rcpf)
    return __builtin_amdgcn_rcpf(v);
#else
    return 1.0f / v;
#endif
}

// LDS-only barrier, single asm: the "memory" clobber pins all memory ops
// (h ds_writes stay above, a ds_reads stay below) but leaves VALU/MFMA
// address-calc free to be scheduled across the wait.
// No vmcnt drain: out-store bursts stay fire-and-forget.
static __device__ __forceinline__ void wg_barrier_lds() {
    asm volatile("s_waitcnt lgkmcnt(0)\n\ts_barrier" ::: "memory");
}

// FINAL (R7 structure, best measured 484-497us; R8's depth-2 chain split
// reverted — neutral-to-negative, chain tail already hidden by co-wave).
// 8 waves: gate wave w owns cols j = w*16+l; batches at C-rows {0,4,8,12}
// -> cell state entirely in C-register 0 (1-reg activation).
// Session ledger (measured):
//  - C-operand chaining at full depth-4 is optimal (R1 depth-1: -35us,
//    R8 depth-2: neutral; matrix-pipe acc forwarding is free)
//  - lgkm-only barrier + prescaled weights (R2: -20us vs vmcnt-drain)
//  - batch-group merge (R3: -64%) and 4-wave-wide (R4: -25%) both lose:
//    narrow per-wave work + 2 waves/SIMD mutual latency-hiding wins
//  - runtime-indexed reg arrays -> scratch, 33x (R5, rule #20)
//  - T14-split refill + gate order {0,2,1,3} (R7: -7us)
// Remaining time is the structural latency floor: ~420cy/step 8-wave
// barrier h-exchange (weights can't fit one wave's registers), ~155cy
// contended MFMA issue, ~150cy ds_read latency, ~150cy activation chain.
// HBM 1%, MfmaUtil 21% — no throughput roofline applies.
__launch_bounds__(NTHR, 2)
__global__ void lstm_mfma_kernel(const float* __restrict__ x,
                                 const float* __restrict__ Wx,
                                 const float* __restrict__ Wh,
                                 const float* __restrict__ b,
                                 const float* __restrict__ Wd,
                                 const float* __restrict__ bd,
                                 float* __restrict__ out) {
    __shared__ __align__(16) char smem[65536];
    const int tid  = threadIdx.x;
    const int wid  = tid >> 6;
    const int lane = tid & 63;
    const int l    = lane & 15;
    const int quad = lane >> 4;
    const int b0   = blockIdx.x * MB;
    const int j    = wid * 16 + l;

    const float L2E = 1.4426950408889634f;

    // ---------- prologue: B fragments staged through LDS ----------
    _Float16* stage = (_Float16*)smem;      // [8][8][512] halves = 64 KB
    half8 bfrag[4][4];                       // wave 7 uses only bfrag[0] (= Wd cols)
#pragma unroll
    for (int pass = 0; pass < 2; ++pass) {
#pragma unroll
        for (int gg = 0; gg < 2; ++gg) {
            const int G = pass * 2 + gg;
            const float gsc = (G == 2) ? (-2.f * L2E) : (-L2E);  // gate pre-scale
#pragma unroll
            for (int kt = 0; kt < 4; ++kt) {
                half8 v;
#pragma unroll
                for (int jj = 0; jj < 8; ++jj) {
                    const int k = kt * 32 + quad * 8 + jj;
                    float w = 0.f;
                    if (wid < 7) {
                        if (j < HID) {
                            if (k < HID)            w = Wh[k * G4 + G * HID + j] * gsc;
                            else if (k < HID + DIN) w = Wx[(k - HID) * G4 + G * HID + j] * gsc;
                        }
                    } else if (G == 0) {
                        if (l < DIN && k < HID)     w = Wd[k * DIN + l];   // unscaled
                    }
                    v[jj] = (_Float16)w;
                }
                *(half8*)&stage[((wid * 8) + (gg * 4 + kt)) * 512 + lane * 8] = v;
            }
        }
        __syncthreads();
#pragma unroll
        for (int gg = 0; gg < 2; ++gg)
#pragma unroll
            for (int kt = 0; kt < 4; ++kt)
                bfrag[pass * 2 + gg][kt] =
                    *(half8*)&stage[((wid * 8) + (gg * 4 + kt)) * 512 + lane * 8];
        __syncthreads();
    }

    // persistent bias-C registers (C operand of the first MFMA in each chain)
    f32x4 biasC[4];
#pragma unroll
    for (int G = 0; G < 4; ++G) biasC[G] = (f32x4){0.f, 0.f, 0.f, 0.f};
    if (wid < 7) {
        if (j < HID) {
#pragma unroll
            for (int G = 0; G < 4; ++G) {
                const float gsc = (G == 2) ? (-2.f * L2E) : (-L2E);
                const float bv = b[G * HID + j] * gsc;
                biasC[G] = (f32x4){bv, bv, bv, bv};
            }
        }
    } else if (l < DIN) {
        const float bv = bd[l];
        biasC[0] = (f32x4){bv, bv, bv, bv};
    }

    // ---------- LDS after prologue: 4-row A dbuf (320B stride) + x chunk ----------
    _Float16 (*Ah)[MB][AROW] = (_Float16 (*)[MB][AROW])smem;     // 2*4*160*2 = 2560 B
    _Float16* xchunk = (_Float16*)(smem + 2560);                 // 64*48*2 = 6144 B

    // T14-split refill: loads one step early into regs, stores next step.
    float4 pre0 = {0.f, 0.f, 0.f, 0.f}, pre1 = {0.f, 0.f, 0.f, 0.f};
    auto refill_load = [&](int c) {   // issue HBM loads for x[c*64 .. +63]
        {
            const int f  = tid;                              // < 768
            const int m  = f / (CHUNK * DIN / 4);            // /192
            const int o  = f - m * (CHUNK * DIN / 4);
            const int tt = o / 3;
            const int dd = o - tt * 3;
            pre0 = *(const float4*)(x +
                ((size_t)(b0 + m) * T_LEN + c * CHUNK + tt) * DIN + dd * 4);
        }
        if (tid < (CHUNK * MB * DIN) / 4 - NTHR) {           // tid < 256
            const int f  = tid + NTHR;
            const int m  = f / (CHUNK * DIN / 4);
            const int o  = f - m * (CHUNK * DIN / 4);
            const int tt = o / 3;
            const int dd = o - tt * 3;
            pre1 = *(const float4*)(x +
                ((size_t)(b0 + m) * T_LEN + c * CHUNK + tt) * DIN + dd * 4);
        }
    };
    auto refill_store = [&]() {       // convert + ds_write (waits vmcnt here)
        {
            const int f  = tid;
            const int m  = f / (CHUNK * DIN / 4);
            const int o  = f - m * (CHUNK * DIN / 4);
            const int tt = o / 3;
            const int dd = o - tt * 3;
            half4_t h4;
            h4[0] = (_Float16)pre0.x; h4[1] = (_Float16)pre0.y;
            h4[2] = (_Float16)pre0.z; h4[3] = (_Float16)pre0.w;
            *(half4_t*)&xchunk[tt * (MB * DIN) + m * DIN + dd * 4] = h4;
        }
        if (tid < (CHUNK * MB * DIN) / 4 - NTHR) {
            const int f  = tid + NTHR;
            const int m  = f / (CHUNK * DIN / 4);
            const int o  = f - m * (CHUNK * DIN / 4);
            const int tt = o / 3;
            const int dd = o - tt * 3;
            half4_t h4;
            h4[0] = (_Float16)pre1.x; h4[1] = (_Float16)pre1.y;
            h4[2] = (_Float16)pre1.z; h4[3] = (_Float16)pre1.w;
            *(half4_t*)&xchunk[tt * (MB * DIN) + m * DIN + dd * 4] = h4;
        }
    };

    for (int i = tid; i < (2 * MB * AROW) / 2; i += NTHR) ((int*)smem)[i] = 0;
    refill_load(0);
    refill_store();
    __syncthreads();
    if (tid < MB * 3) {           // stage x[0]
        const int m = tid / 3, part = tid - (tid / 3) * 3;
        *(half4_t*)&Ah[0][m][HID + part * 4] =
            *(const half4_t*)&xchunk[m * DIN + part * 4];
    }
    __syncthreads();

    const bool gate_lane = (wid < 7) && (j < HID);
    const int  arow = l >> 2;

    float cs = 0.f;               // scaled cell state  c' = -2*log2e * c
    float obuf[UNROLL];

#pragma unroll 1
    for (int tb = 0; tb < T_LEN / UNROLL; ++tb) {
        const bool do_refill = (((tb + 1) & 7) == 0) && ((tb + 1) < T_LEN / UNROLL);
#pragma unroll
        for (int it = 0; it < UNROLL; ++it) {
            const int t  = tb * UNROLL + it;     // always < T_LEN here
            const int p  = it & 1;               // compile-time parity
            const int pn = p ^ 1;

            if (it == UNROLL - 2) {
                if (do_refill) refill_load((tb + 1) >> 3);   // loads in flight 1 step
            }
            if (it == UNROLL - 1) {
                if (do_refill) {
                    refill_store();               // vmcnt covered by prev step
                    wg_barrier_lds();
                }
            }

            half8 a[4];
#pragma unroll
            for (int kt = 0; kt < 4; ++kt)
                a[kt] = *(const half8*)&Ah[p][arow][kt * 32 + quad * 8];

            if (wid < 7) {
                f32x4 acc[4];
                // kt outer / ordered G inner (all indices compile-time):
                // completion order {0,2,1,3} — g-gate (longest activation
                // sub-chain) finishes early, o-gate (consumed last) finishes
                // last. Chains start from biasC; C-operand chaining stays in
                // the matrix pipe (acc forwarding).
#pragma unroll
                for (int kt = 0; kt < 4; ++kt)
#pragma unroll
                    for (int Gi = 0; Gi < 4; ++Gi) {
                        constexpr int GO_[4] = {0, 2, 1, 3};
                        const int G = GO_[Gi];   // compile-time after unroll
                        acc[G] = __builtin_amdgcn_mfma_f32_16x16x32_f16(
                                     a[kt], bfrag[G][kt],
                                     (kt == 0) ? biasC[G] : acc[G], 0, 0, 0);
                    }

                if (gate_lane) {
                    // pre-scaled: zi,zf,zo = -log2e * a ; zg = -2log2e * a
                    const float ei = fast_exp2(acc[0][0]);
                    const float ef = fast_exp2(acc[1][0]);
                    const float eg = fast_exp2(acc[2][0]);
                    const float eo = fast_exp2(acc[3][0]);
                    const float gf  = fast_rcp(1.f + ef);
                    const float dd  = (1.f + ei) * (1.f + eg);
                    const float u   = __builtin_fmaf(eg, 2.f * L2E, -2.f * L2E); // -2log2e*(1-eg)
                    const float gig = u * fast_rcp(dd);          // -2log2e * sig(i)*tanh(g)
                    cs = __builtin_fmaf(gf, cs, gig);            // c' = gf*c' + gig'
                    const float ec = fast_exp2(cs);              // e^{-2 c}
                    const float hv = (1.f - ec) * fast_rcp((1.f + eo) * (1.f + ec));
                    Ah[pn][quad][j] = (_Float16)hv;
                }
            } else {
                // wave 7: stage x[t+1] FIRST (independent of a[]), so the
                // LDS write latency hides under the projection MFMAs.
                if ((t + 1) < T_LEN && lane < MB * 3) {
                    const int m = lane / 3, part = lane - (lane / 3) * 3;
                    *(half4_t*)&Ah[pn][m][HID + part * 4] =
                        *(const half4_t*)&xchunk[((t + 1) & (CHUNK - 1)) * (MB * DIN)
                                                 + m * DIN + part * 4];
                }
                f32x4 accP;
#pragma unroll
                for (int kt = 0; kt < 4; ++kt)
                    accP = __builtin_amdgcn_mfma_f32_16x16x32_f16(
                               a[kt], bfrag[0][kt],
                               (kt == 0) ? biasC[0] : accP, 0, 0, 0);
                obuf[it] = accP[0];               // out row t-1, batch=quad, col=l
            }
            wg_barrier_lds();
        }
        if (wid == 7 && l < DIN) {
            // burst stores, never drained (lgkm-only barriers) -> fire-and-forget
#pragma unroll
            for (int s = 0; s < UNROLL; ++s) {
                const int row = tb * UNROLL + s - 1;
                if (row >= 0)
                    out[((size_t)(b0 + quad) * T_LEN + row) * DIN + l] = obuf[s];
            }
        }
    }

    // ---------- epilogue: projection of h_{T-1} -> out row T-1 ----------
    if (wid == 7) {
        half8 a[4];
#pragma unroll
        for (int kt = 0; kt < 4; ++kt)
            a[kt] = *(const half8*)&Ah[0][arow][kt * 32 + quad * 8];
        f32x4 accP;
#pragma unroll
        for (int kt = 0; kt < 4; ++kt)
            accP = __builtin_amdgcn_mfma_f32_16x16x32_f16(
                       a[kt], bfrag[0][kt],
                       (kt == 0) ? biasC[0] : accP, 0, 0, 0);
        if (l < DIN)
            out[((size_t)(b0 + quad) * T_LEN + (T_LEN - 1)) * DIN + l] = accP[0];
    }
}

extern "C" void kernel_launch(void* const* d_in, const int* in_sizes, int n_in,
                              void* d_out, int out_size, void* d_ws, size_t ws_size,
                              hipStream_t stream) {
    const float* x  = (const float*)d_in[0];
    const float* Wx = (const float*)d_in[1];
    const float* Wh = (const float*)d_in[2];
    const float* b  = (const float*)d_in[3];
    const float* Wd = (const float*)d_in[4];
    const float* bd = (const float*)d_in[5];
    float* out = (float*)d_out;

    lstm_mfma_kernel<<<NBLK, NTHR, 0, stream>>>(x, Wx, Wh, b, Wd, bd, out);
}

// Round 10
// 527.277 us; speedup vs baseline: 1.0073x; 1.0066x over previous
//
#include <hip/hip_runtime.h>
#include <math.h>

#define T_LEN 1024
#define BATCH 512
#define DIN   12
#define HID   100
#define G4    400
#define MB    4                   // batches per block, at C-rows {0,4,8,12}
#define NBLK  (BATCH / MB)        // 128
#define AROW  160                 // halves per A row -> 320 B stride
#define NW    7                   // 7 waves: projection folded into wave 6
#define NTHR  (NW * 64)           // 448
#define CHUNK 64
#define UNROLL 8

typedef _Float16 half8   __attribute__((ext_vector_type(8)));
typedef _Float16 half4_t __attribute__((ext_vector_type(4)));
typedef float    f32x4   __attribute__((ext_vector_type(4)));

static __device__ __forceinline__ float fast_exp2(float v) {
#if __has_builtin(__builtin_amdgcn_exp2f)
    return __builtin_amdgcn_exp2f(v);
#else
    return exp2f(v);
#endif
}
static __device__ __forceinline__ float fast_rcp(float v) {
#if __has_builtin(__builtin_amdgcn_rcpf)
    return __builtin_amdgcn_rcpf(v);
#else
    return 1.0f / v;
#endif
}

// LDS-only barrier, single asm: the "memory" clobber pins all memory ops
// (h ds_writes stay above, a ds_reads stay below) but leaves VALU/MFMA
// address-calc free to be scheduled across the wait.
// No vmcnt drain: out-store bursts stay fire-and-forget.
static __device__ __forceinline__ void wg_barrier_lds() {
    asm volatile("s_waitcnt lgkmcnt(0)\n\ts_barrier" ::: "memory");
}

// Round-10 structural trim: 7 WAVES (was 8). Wave 6's gate tile only uses
// cols l<4 (j=96..99); its l=4..15 B-columns were zeros. The Wd projection
// uses the SAME A-fragment as the gates at the same step, so Wd's 12 cols
// (unscaled, k<100) are packed into bfrag[0] cols l=4..15 of wave 6 and bd
// into those lanes' biasC[0] — wave 6's unchanged 16-MFMA chain now yields
// gates (l<4) AND projection (l>=4) together. The former wave 7 (4 MFMAs +
// staging + stores) is deleted: one fewer barrier arrival per step, and x
// staging / store bursts move to wave 6's non-cell lanes.
// Session ledger (measured):
//  - C-operand chaining at full depth-4 optimal (R1 depth-1 -35us, R8
//    depth-2 neutral; matrix-pipe acc forwarding is free)
//  - lgkm-only barrier + prescaled weights (R2)
//  - batch-group merge (R3 -64%) / 4-wave-wide (R4 -25%) lose: narrow
//    per-wave work + 2 waves/SIMD mutual latency-hiding wins
//  - runtime-indexed reg arrays -> scratch 33x (R5, rule #20)
//  - T14-split refill + gate order {0,2,1,3} (R7)
__launch_bounds__(NTHR, 2)
__global__ void lstm_mfma_kernel(const float* __restrict__ x,
                                 const float* __restrict__ Wx,
                                 const float* __restrict__ Wh,
                                 const float* __restrict__ b,
                                 const float* __restrict__ Wd,
                                 const float* __restrict__ bd,
                                 float* __restrict__ out) {
    __shared__ __align__(16) char smem[65536];
    const int tid  = threadIdx.x;
    const int wid  = tid >> 6;
    const int lane = tid & 63;
    const int l    = lane & 15;
    const int quad = lane >> 4;
    const int b0   = blockIdx.x * MB;
    const int j    = wid * 16 + l;

    const float L2E = 1.4426950408889634f;

    // ---------- prologue: B fragments staged through LDS ----------
    _Float16* stage = (_Float16*)smem;      // [7][8][512] halves = 57344 B
    half8 bfrag[4][4];   // wave 6: bfrag[0] cols l>=4 hold Wd (unscaled)
#pragma unroll
    for (int pass = 0; pass < 2; ++pass) {
#pragma unroll
        for (int gg = 0; gg < 2; ++gg) {
            const int G = pass * 2 + gg;
            const float gsc = (G == 2) ? (-2.f * L2E) : (-L2E);  // gate pre-scale
#pragma unroll
            for (int kt = 0; kt < 4; ++kt) {
                half8 v;
#pragma unroll
                for (int jj = 0; jj < 8; ++jj) {
                    const int k = kt * 32 + quad * 8 + jj;
                    float w = 0.f;
                    if (wid < 6 || l < 4) {          // gate columns (j < HID)
                        if (j < HID) {
                            if (k < HID)            w = Wh[k * G4 + G * HID + j] * gsc;
                            else if (k < HID + DIN) w = Wx[(k - HID) * G4 + G * HID + j] * gsc;
                        }
                    } else if (G == 0) {             // wave 6, l>=4: Wd col l-4
                        if (k < HID)                w = Wd[k * DIN + (l - 4)];
                    }
                    v[jj] = (_Float16)w;
                }
                *(half8*)&stage[((wid * 8) + (gg * 4 + kt)) * 512 + lane * 8] = v;
            }
        }
        __syncthreads();
#pragma unroll
        for (int gg = 0; gg < 2; ++gg)
#pragma unroll
            for (int kt = 0; kt < 4; ++kt)
                bfrag[pass * 2 + gg][kt] =
                    *(half8*)&stage[((wid * 8) + (gg * 4 + kt)) * 512 + lane * 8];
        __syncthreads();
    }

    // persistent bias-C registers (C operand of the first MFMA in each chain)
    f32x4 biasC[4];
#pragma unroll
    for (int G = 0; G < 4; ++G) biasC[G] = (f32x4){0.f, 0.f, 0.f, 0.f};
    if (wid < 6 || l < 4) {
        if (j < HID) {
#pragma unroll
            for (int G = 0; G < 4; ++G) {
                const float gsc = (G == 2) ? (-2.f * L2E) : (-L2E);
                const float bv = b[G * HID + j] * gsc;
                biasC[G] = (f32x4){bv, bv, bv, bv};
            }
        }
    } else {                                  // wave 6, l>=4: projection bias
        const float bv = bd[l - 4];
        biasC[0] = (f32x4){bv, bv, bv, bv};
    }

    // ---------- LDS after prologue: 4-row A dbuf (320B stride) + x chunk ----------
    _Float16 (*Ah)[MB][AROW] = (_Float16 (*)[MB][AROW])smem;     // 2*4*160*2 = 2560 B
    _Float16* xchunk = (_Float16*)(smem + 2560);                 // 64*48*2 = 6144 B

    // T14-split refill: loads one step early into regs, stores next step.
    float4 pre0 = {0.f, 0.f, 0.f, 0.f}, pre1 = {0.f, 0.f, 0.f, 0.f};
    auto refill_load = [&](int c) {   // issue HBM loads for x[c*64 .. +63]
        {
            const int f  = tid;                              // < 768
            const int m  = f / (CHUNK * DIN / 4);            // /192
            const int o  = f - m * (CHUNK * DIN / 4);
            const int tt = o / 3;
            const int dd = o - tt * 3;
            pre0 = *(const float4*)(x +
                ((size_t)(b0 + m) * T_LEN + c * CHUNK + tt) * DIN + dd * 4);
        }
        if (tid < (CHUNK * MB * DIN) / 4 - NTHR) {           // tid < 320
            const int f  = tid + NTHR;
            const int m  = f / (CHUNK * DIN / 4);
            const int o  = f - m * (CHUNK * DIN / 4);
            const int tt = o / 3;
            const int dd = o - tt * 3;
            pre1 = *(const float4*)(x +
                ((size_t)(b0 + m) * T_LEN + c * CHUNK + tt) * DIN + dd * 4);
        }
    };
    auto refill_store = [&]() {       // convert + ds_write (waits vmcnt here)
        {
            const int f  = tid;
            const int m  = f / (CHUNK * DIN / 4);
            const int o  = f - m * (CHUNK * DIN / 4);
            const int tt = o / 3;
            const int dd = o - tt * 3;
            half4_t h4;
            h4[0] = (_Float16)pre0.x; h4[1] = (_Float16)pre0.y;
            h4[2] = (_Float16)pre0.z; h4[3] = (_Float16)pre0.w;
            *(half4_t*)&xchunk[tt * (MB * DIN) + m * DIN + dd * 4] = h4;
        }
        if (tid < (CHUNK * MB * DIN) / 4 - NTHR) {
            const int f  = tid + NTHR;
            const int m  = f / (CHUNK * DIN / 4);
            const int o  = f - m * (CHUNK * DIN / 4);
            const int tt = o / 3;
            const int dd = o - tt * 3;
            half4_t h4;
            h4[0] = (_Float16)pre1.x; h4[1] = (_Float16)pre1.y;
            h4[2] = (_Float16)pre1.z; h4[3] = (_Float16)pre1.w;
            *(half4_t*)&xchunk[tt * (MB * DIN) + m * DIN + dd * 4] = h4;
        }
    };

    for (int i = tid; i < (2 * MB * AROW) / 2; i += NTHR) ((int*)smem)[i] = 0;
    refill_load(0);
    refill_store();
    __syncthreads();
    if (tid < MB * 3) {           // stage x[0]
        const int m = tid / 3, part = tid - (tid / 3) * 3;
        *(half4_t*)&Ah[0][m][HID + part * 4] =
            *(const half4_t*)&xchunk[m * DIN + part * 4];
    }
    __syncthreads();

    const bool gate_lane = (j < HID);        // all 7 waves; wave 6: l<4 only
    const bool proj_lane = (wid == 6) && (l >= 4);
    const bool stag_lane = (wid == 6) && (lane >= 20) && (lane < 32); // quad1 l4-15
    const int  arow = l >> 2;

    float cs = 0.f;               // scaled cell state  c' = -2*log2e * c
    float obuf[UNROLL];

#pragma unroll 1
    for (int tb = 0; tb < T_LEN / UNROLL; ++tb) {
        const bool do_refill = (((tb + 1) & 7) == 0) && ((tb + 1) < T_LEN / UNROLL);
#pragma unroll
        for (int it = 0; it < UNROLL; ++it) {
            const int t  = tb * UNROLL + it;     // always < T_LEN here
            const int p  = it & 1;               // compile-time parity
            const int pn = p ^ 1;

            if (it == UNROLL - 2) {
                if (do_refill) refill_load((tb + 1) >> 3);   // loads in flight 1 step
            }
            if (it == UNROLL - 1) {
                if (do_refill) {
                    refill_store();               // vmcnt covered by prev step
                    wg_barrier_lds();
                }
            }

            half8 a[4];
#pragma unroll
            for (int kt = 0; kt < 4; ++kt)
                a[kt] = *(const half8*)&Ah[p][arow][kt * 32 + quad * 8];

            // wave 6: stage x[t+1] early (independent of this step's a[]),
            // LDS write latency hides under the MFMAs below.
            if (stag_lane && (t + 1) < T_LEN) {
                const int idx = lane - 20;
                const int m = idx / 3, part = idx - (idx / 3) * 3;
                *(half4_t*)&Ah[pn][m][HID + part * 4] =
                    *(const half4_t*)&xchunk[((t + 1) & (CHUNK - 1)) * (MB * DIN)
                                             + m * DIN + part * 4];
            }

            f32x4 acc[4];
            // kt outer / ordered G inner (all indices compile-time):
            // completion order {0,2,1,3}. Chains start from biasC; C-operand
            // chaining stays in the matrix pipe (acc forwarding). Wave 6's
            // acc[0] also carries the projection in cols l>=4.
#pragma unroll
            for (int kt = 0; kt < 4; ++kt)
#pragma unroll
                for (int Gi = 0; Gi < 4; ++Gi) {
                    constexpr int GO_[4] = {0, 2, 1, 3};
                    const int G = GO_[Gi];   // compile-time after unroll
                    acc[G] = __builtin_amdgcn_mfma_f32_16x16x32_f16(
                                 a[kt], bfrag[G][kt],
                                 (kt == 0) ? biasC[G] : acc[G], 0, 0, 0);
                }

            if (gate_lane) {
                // pre-scaled: zi,zf,zo = -log2e * a ; zg = -2log2e * a
                const float ei = fast_exp2(acc[0][0]);
                const float ef = fast_exp2(acc[1][0]);
                const float eg = fast_exp2(acc[2][0]);
                const float eo = fast_exp2(acc[3][0]);
                const float gf  = fast_rcp(1.f + ef);
                const float dd  = (1.f + ei) * (1.f + eg);
                const float u   = __builtin_fmaf(eg, 2.f * L2E, -2.f * L2E); // -2log2e*(1-eg)
                const float gig = u * fast_rcp(dd);          // -2log2e * sig(i)*tanh(g)
                cs = __builtin_fmaf(gf, cs, gig);            // c' = gf*c' + gig'
                const float ec = fast_exp2(cs);              // e^{-2 c}
                const float hv = (1.f - ec) * fast_rcp((1.f + eo) * (1.f + ec));
                Ah[pn][quad][j] = (_Float16)hv;
            }
            if (proj_lane)
                obuf[it] = acc[0][0];     // out row t-1, batch=quad, col=l-4

            wg_barrier_lds();
        }
        if (proj_lane) {
            // burst stores, never drained (lgkm-only barriers) -> fire-and-forget
#pragma unroll
            for (int s = 0; s < UNROLL; ++s) {
                const int row = tb * UNROLL + s - 1;
                if (row >= 0)
                    out[((size_t)(b0 + quad) * T_LEN + row) * DIN + (l - 4)] = obuf[s];
            }
        }
    }

    // ---------- epilogue: projection of h_{T-1} -> out row T-1 ----------
    if (wid == 6) {
        half8 a[4];
#pragma unroll
        for (int kt = 0; kt < 4; ++kt)
            a[kt] = *(const half8*)&Ah[0][arow][kt * 32 + quad * 8];
        f32x4 accP;
#pragma unroll
        for (int kt = 0; kt < 4; ++kt)
            accP = __builtin_amdgcn_mfma_f32_16x16x32_f16(
                       a[kt], bfrag[0][kt],
                       (kt == 0) ? biasC[0] : accP, 0, 0, 0);
        if (l >= 4)
            out[((size_t)(b0 + quad) * T_LEN + (T_LEN - 1)) * DIN + (l - 4)] = accP[0];
    }
}

extern "C" void kernel_launch(void* const* d_in, const int* in_sizes, int n_in,
                              void* d_out, int out_size, void* d_ws, size_t ws_size,
                              hipStream_t stream) {
    const float* x  = (const float*)d_in[0];
    const float* Wx = (const float*)d_in[1];
    const float* Wh = (const float*)d_in[2];
    const float* b  = (const float*)d_in[3];
    const float* Wd = (const float*)d_in[4];
    const float* bd = (const float*)d_in[5];
    float* out = (float*)d_out;

    lstm_mfma_kernel<<<NBLK, NTHR, 0, stream>>>(x, Wx, Wh, b, Wd, bd, out);
}